// Round 2
// baseline (229.190 us; speedup 1.0000x reference)
//
#include <hip/hip_runtime.h>

// IWT (inverse 2x2 Haar): x (32, 256, 64, 64) f32 -> out (32, 64, 128, 128) f32
// Input channel dim = 64 groups * 4 subbands {cA, cH, cV, cD}.
// out[2h  ][2w  ] = (a + h + v + d) * 0.5
// out[2h  ][2w+1] = (a + h - v - d) * 0.5
// out[2h+1][2w  ] = (a - h + v - d) * 0.5
// out[2h+1][2w+1] = (a - h - v + d) * 0.5

#define BB 32
#define CC 64
#define HH 64
#define WW 64

__global__ __launch_bounds__(256) void iwt_kernel(const float* __restrict__ x,
                                                  float* __restrict__ out) {
    // Each thread handles 4 consecutive w elements (one float4 per subband).
    const int W4 = WW / 4;  // 16
    int tid = blockIdx.x * blockDim.x + threadIdx.x;

    int w4 = tid & (W4 - 1);          // 0..15
    int h  = (tid >> 4) & (HH - 1);   // 0..63
    int bc = tid >> 10;               // 0 .. B*C-1 (2047)
    if (bc >= BB * CC) return;

    const float4* __restrict__ xv = (const float4*)x;
    // float idx for subband s: (4*bc + s)*4096 + h*64 + 4*w4
    // -> float4 idx: (4*bc + s)*1024 + h*16 + w4
    int base = (bc << 12) + (h << 4) + w4;  // 4*bc*1024 = bc<<12
    float4 a = xv[base];
    float4 hv = xv[base + 1024];
    float4 v = xv[base + 2048];
    float4 d = xv[base + 3072];

    float4 o00, o01, o10, o11;
    o00.x = (a.x + hv.x + v.x + d.x) * 0.5f;
    o01.x = (a.x + hv.x - v.x - d.x) * 0.5f;
    o10.x = (a.x - hv.x + v.x - d.x) * 0.5f;
    o11.x = (a.x - hv.x - v.x + d.x) * 0.5f;
    o00.y = (a.y + hv.y + v.y + d.y) * 0.5f;
    o01.y = (a.y + hv.y - v.y - d.y) * 0.5f;
    o10.y = (a.y - hv.y + v.y - d.y) * 0.5f;
    o11.y = (a.y - hv.y - v.y + d.y) * 0.5f;
    o00.z = (a.z + hv.z + v.z + d.z) * 0.5f;
    o01.z = (a.z + hv.z - v.z - d.z) * 0.5f;
    o10.z = (a.z - hv.z + v.z - d.z) * 0.5f;
    o11.z = (a.z - hv.z - v.z + d.z) * 0.5f;
    o00.w = (a.w + hv.w + v.w + d.w) * 0.5f;
    o01.w = (a.w + hv.w - v.w - d.w) * 0.5f;
    o10.w = (a.w - hv.w + v.w - d.w) * 0.5f;
    o11.w = (a.w - hv.w - v.w + d.w) * 0.5f;

    float4* __restrict__ ov = (float4*)out;
    // out float idx row y, x: bc*16384 + y*128 + x  -> float4 idx: (bc*128+y)*32 + x/4
    // this thread covers x = 8*w4 .. 8*w4+7  -> float4 idx offset 2*w4, 2*w4+1
    int y0 = (bc << 7) + (h << 1);            // row 2h
    int obase0 = (y0 << 5) + (w4 << 1);       // row 2h, first of 2 float4
    int obase1 = obase0 + 32;                 // row 2h+1 (one row = 32 float4)

    float4 r0a = make_float4(o00.x, o01.x, o00.y, o01.y);
    float4 r0b = make_float4(o00.z, o01.z, o00.w, o01.w);
    float4 r1a = make_float4(o10.x, o11.x, o10.y, o11.y);
    float4 r1b = make_float4(o10.z, o11.z, o10.w, o11.w);

    ov[obase0]     = r0a;
    ov[obase0 + 1] = r0b;
    ov[obase1]     = r1a;
    ov[obase1 + 1] = r1b;
}

extern "C" void kernel_launch(void* const* d_in, const int* in_sizes, int n_in,
                              void* d_out, int out_size, void* d_ws, size_t ws_size,
                              hipStream_t stream) {
    const float* x = (const float*)d_in[0];
    float* out = (float*)d_out;

    const int total_threads = BB * CC * HH * (WW / 4);  // 2,097,152
    const int block = 256;
    const int grid = total_threads / block;             // 8192

    iwt_kernel<<<grid, block, 0, stream>>>(x, out);
}

// Round 3
// 223.868 us; speedup vs baseline: 1.0238x; 1.0238x over previous
//
#include <hip/hip_runtime.h>

// IWT (inverse 2x2 Haar): x (32, 256, 64, 64) f32 -> out (32, 64, 128, 128) f32
// Input channel dim = 64 groups * 4 subbands {cA, cH, cV, cD}.
// out[2h  ][2w  ] = (a + h + v + d) * 0.5
// out[2h  ][2w+1] = (a + h - v - d) * 0.5
// out[2h+1][2w  ] = (a - h + v - d) * 0.5
// out[2h+1][2w+1] = (a - h - v + d) * 0.5
//
// Lane mapping chosen so every vmem instruction is fully dense across the wave:
//   thread -> input float2 (w = 2*w2, 2*w2+1); loads: 4x dwordx2, wave covers
//   512B contiguous per load. Stores: one float4 per output row at idx base+w2;
//   wave store = two dense 512B segments (rows 2h and 2h+2 interleave across
//   half-waves). No strided/gappy instructions anywhere.

#define BB 32
#define CC 64
#define HH 64
#define WW 64

__global__ __launch_bounds__(256) void iwt_kernel(const float* __restrict__ x,
                                                  float* __restrict__ out) {
    int tid = blockIdx.x * blockDim.x + threadIdx.x;

    int w2 = tid & 31;           // which float2 within the input row (0..31)
    int h  = (tid >> 5) & 63;    // input row
    int bc = tid >> 11;          // 0 .. B*C-1 (2047)

    const float2* __restrict__ xv = (const float2*)x;
    // float idx for subband s: (4*bc + s)*4096 + h*64 + 2*w2
    // -> float2 idx: (4*bc + s)*2048 + h*32 + w2
    int base = (bc << 13) + (h << 5) + w2;
    float2 a  = xv[base];
    float2 hh = xv[base + 2048];
    float2 v  = xv[base + 4096];
    float2 d  = xv[base + 6144];

    // butterfly: p=a+d, q=a-d, r=h+v, s=h-v
    // o00=(p+r)/2, o01=(q+s)/2, o10=(q-s)/2, o11=(p-r)/2
    float px = a.x + d.x, qx = a.x - d.x, rx = hh.x + v.x, sx = hh.x - v.x;
    float py = a.y + d.y, qy = a.y - d.y, ry = hh.y + v.y, sy = hh.y - v.y;

    float4 r0, r1;
    r0.x = (px + rx) * 0.5f;   // o00 (w=2*w2)
    r0.y = (qx + sx) * 0.5f;   // o01
    r0.z = (py + ry) * 0.5f;   // o00 (w=2*w2+1)
    r0.w = (qy + sy) * 0.5f;   // o01
    r1.x = (qx - sx) * 0.5f;   // o10
    r1.y = (px - rx) * 0.5f;   // o11
    r1.z = (qy - sy) * 0.5f;   // o10
    r1.w = (py - ry) * 0.5f;   // o11

    float4* __restrict__ ov = (float4*)out;
    // out float4 idx for row y: (bc*128 + y)*32 + w2
    // row 2h:  bc*4096 + h*64 + w2 ; row 2h+1: +32
    int obase0 = (bc << 12) + (h << 6) + w2;
    ov[obase0]      = r0;
    ov[obase0 + 32] = r1;
}

extern "C" void kernel_launch(void* const* d_in, const int* in_sizes, int n_in,
                              void* d_out, int out_size, void* d_ws, size_t ws_size,
                              hipStream_t stream) {
    const float* x = (const float*)d_in[0];
    float* out = (float*)d_out;

    const int total_threads = BB * CC * HH * (WW / 2);  // 4,194,304
    const int block = 256;
    const int grid = total_threads / block;             // 16384

    iwt_kernel<<<grid, block, 0, stream>>>(x, out);
}